// Round 1
// baseline (24816.200 us; speedup 1.0000x reference)
//
#include <hip/hip_runtime.h>

// ODE-GRU on MI355X. One workgroup per batch row (B=512 WGs, 256 thr each),
// entire SEQ=256 reverse scan inside one kernel. Thread j owns h[j]; drift
// weights W1/W2 live in per-thread registers (64+64 floats); W_hh/W_ih
// stream from L2 each step. fp32 VALU throughout (round-1 correctness-first).

#define SEQ   256
#define BATCH 512
#define DIN   54
#define HDIM  256
#define DH    64
#define NODE  8

__device__ __forceinline__ float fast_tanh(float x) {
    x = fminf(15.0f, fmaxf(-15.0f, x));
    float e = __expf(2.0f * x);
    return (e - 1.0f) / (e + 1.0f);
}
__device__ __forceinline__ float fast_sigmoid(float x) {
    x = fminf(30.0f, fmaxf(-30.0f, x));
    float e = __expf(-x);
    return 1.0f / (1.0f + e);
}

// One drift eval: y (per-thread scalar, thread tid owns y[tid]) -> k (per-thread).
// ylds write ... B1 ... stage1 (read ylds, shuffle-reduce, tanh, write ulds)
// ... B2 ... stage2 (broadcast-read ulds). Exactly 2 barriers. Race-free:
// stage1 ylds reads complete before B2; next drift's ylds write is after B2.
#define DRIFT(Y_EXPR, KOUT) do {                                              \
    ylds[tid] = (Y_EXPR);                                                     \
    __syncthreads();                                                          \
    float acc_ = 0.0f;                                                        \
    const float4* yy_ = (const float4*)(ylds + kc * 64);                      \
    _Pragma("unroll")                                                         \
    for (int q_ = 0; q_ < 16; ++q_) {                                         \
        float4 yv_ = yy_[q_];                                                 \
        acc_ = fmaf(w1v[q_].x, yv_.x, acc_);                                  \
        acc_ = fmaf(w1v[q_].y, yv_.y, acc_);                                  \
        acc_ = fmaf(w1v[q_].z, yv_.z, acc_);                                  \
        acc_ = fmaf(w1v[q_].w, yv_.w, acc_);                                  \
    }                                                                         \
    acc_ += __shfl_xor(acc_, 1);                                              \
    acc_ += __shfl_xor(acc_, 2);                                              \
    float uu_ = fast_tanh(acc_ + b1r);                                        \
    if (kc == 0) ulds[j1] = uu_;                                              \
    __syncthreads();                                                          \
    float acc2_ = b2r;                                                        \
    const float4* uu4_ = (const float4*)ulds;                                 \
    _Pragma("unroll")                                                         \
    for (int q_ = 0; q_ < 16; ++q_) {                                         \
        float4 uv_ = uu4_[q_];                                                \
        acc2_ = fmaf(w2v[q_].x, uv_.x, acc2_);                                \
        acc2_ = fmaf(w2v[q_].y, uv_.y, acc2_);                                \
        acc2_ = fmaf(w2v[q_].z, uv_.z, acc2_);                                \
        acc2_ = fmaf(w2v[q_].w, uv_.w, acc2_);                                \
    }                                                                         \
    KOUT = acc2_;                                                             \
} while (0)

__global__ __launch_bounds__(256, 2)
void odegru_kernel(const float* __restrict__ x,
                   const float* __restrict__ tvec,
                   const float* __restrict__ W_ih,
                   const float* __restrict__ W_hh,
                   const float* __restrict__ b_ih,
                   const float* __restrict__ b_hh,
                   const float* __restrict__ W1,
                   const float* __restrict__ b1,
                   const float* __restrict__ W2,
                   const float* __restrict__ b2,
                   float* __restrict__ out)
{
    const int tid = threadIdx.x;
    const int b   = blockIdx.x;
    const int j1  = tid >> 2;   // drift stage-1 output index (0..63)
    const int kc  = tid & 3;    // drift stage-1 k-chunk (0..3)

    __shared__ float ylds[HDIM];
    __shared__ float ulds[DH];
    __shared__ float xlds[DIN];

    // Drift weights -> registers. Stage1: thread needs W1[j1][kc*64 .. +63].
    // Stage2: thread needs W2[tid][0..63]. Both rows 16B-aligned.
    float4 w1v[16];
    {
        const float4* W1r = (const float4*)(W1 + j1 * HDIM + kc * 64);
        #pragma unroll
        for (int q = 0; q < 16; ++q) w1v[q] = W1r[q];
    }
    float4 w2v[16];
    {
        const float4* W2r = (const float4*)(W2 + tid * DH);
        #pragma unroll
        for (int q = 0; q < 16; ++q) w2v[q] = W2r[q];
    }

    const float b1r  = b1[j1];
    const float b2r  = b2[tid];
    const float bihr = b_ih[tid], bihz = b_ih[tid + HDIM], bihn = b_ih[tid + 2 * HDIM];
    const float bhhr = b_hh[tid], bhhz = b_hh[tid + HDIM], bhhn = b_hh[tid + 2 * HDIM];

    // GRU weight row pointers (rows: tid, tid+256, tid+512).
    const float4* whr = (const float4*)(W_hh + (size_t)tid * HDIM);
    const float4* whz = (const float4*)(W_hh + (size_t)(tid + HDIM) * HDIM);
    const float4* whn = (const float4*)(W_hh + (size_t)(tid + 2 * HDIM) * HDIM);
    const float2* wir = (const float2*)(W_ih + (size_t)tid * DIN);
    const float2* wiz = (const float2*)(W_ih + (size_t)(tid + HDIM) * DIN);
    const float2* win = (const float2*)(W_ih + (size_t)(tid + 2 * HDIM) * DIN);

    float h = 0.0f;

    for (int i = 0; i < SEQ; ++i) {
        const int s = SEQ - 1 - i;   // source (and output) time index

        if (tid < DIN) xlds[tid] = x[((size_t)s * BATCH + b) * DIN + tid];
        ylds[tid] = h;
        __syncthreads();

        // ---- GRU ----
        float gir = bihr, giz = bihz, gin = bihn;
        #pragma unroll
        for (int q = 0; q < 27; ++q) {   // 54 = 27 * 2, rows are 8B-aligned
            float2 a = wir[q], c = wiz[q], d = win[q];
            float x0 = xlds[2 * q], x1 = xlds[2 * q + 1];
            gir = fmaf(a.x, x0, gir); gir = fmaf(a.y, x1, gir);
            giz = fmaf(c.x, x0, giz); giz = fmaf(c.y, x1, giz);
            gin = fmaf(d.x, x0, gin); gin = fmaf(d.y, x1, gin);
        }
        float ghr = bhhr, ghz = bhhz, ghn = bhhn;
        {
            const float4* y4 = (const float4*)ylds;
            #pragma unroll 8
            for (int q = 0; q < 64; ++q) {
                float4 hv = y4[q];
                float4 a = whr[q], c = whz[q], d = whn[q];
                ghr = fmaf(a.x, hv.x, fmaf(a.y, hv.y, fmaf(a.z, hv.z, fmaf(a.w, hv.w, ghr))));
                ghz = fmaf(c.x, hv.x, fmaf(c.y, hv.y, fmaf(c.z, hv.z, fmaf(c.w, hv.w, ghz))));
                ghn = fmaf(d.x, hv.x, fmaf(d.y, hv.y, fmaf(d.z, hv.z, fmaf(d.w, hv.w, ghn))));
            }
        }
        float r = fast_sigmoid(gir + ghr);
        float z = fast_sigmoid(giz + ghz);
        float n = fast_tanh(gin + r * ghn);
        h = n + z * (h - n);

        // ---- ODE integrate (dopri5, 8 fixed steps) ----
        const float t0v = tvec[s];
        const float t1v = (s > 0) ? tvec[s - 1] : tvec[0];
        const float dt  = (t1v - t0v) * (1.0f / NODE);

        if (dt != 0.0f) {   // block-uniform; dt==0 only at s==0 (exact skip)
            for (int st = 0; st < NODE; ++st) {
                float k1, k2, k3, k4, k5, k6;
                DRIFT(h, k1);
                DRIFT(fmaf(dt * 0.2f, k1, h), k2);
                DRIFT(h + dt * (0.075f * k1 + 0.225f * k2), k3);
                DRIFT(h + dt * ((44.0f/45.0f) * k1 + (-56.0f/15.0f) * k2
                              + (32.0f/9.0f)  * k3), k4);
                DRIFT(h + dt * ((19372.0f/6561.0f) * k1 + (-25360.0f/2187.0f) * k2
                              + (64448.0f/6561.0f) * k3 + (-212.0f/729.0f)   * k4), k5);
                DRIFT(h + dt * ((9017.0f/3168.0f)  * k1 + (-355.0f/33.0f)    * k2
                              + (46732.0f/5247.0f) * k3 + (49.0f/176.0f)     * k4
                              + (-5103.0f/18656.0f)* k5), k6);
                h = h + dt * ((35.0f/384.0f)    * k1 + (500.0f/1113.0f)  * k3
                            + (125.0f/192.0f)   * k4 + (-2187.0f/6784.0f) * k5
                            + (11.0f/84.0f)     * k6);
            }
        }

        out[((size_t)s * BATCH + b) * HDIM + tid] = h;
        __syncthreads();   // protect next iteration's ylds/xlds writes
    }
}

extern "C" void kernel_launch(void* const* d_in, const int* in_sizes, int n_in,
                              void* d_out, int out_size, void* d_ws, size_t ws_size,
                              hipStream_t stream) {
    const float* x    = (const float*)d_in[0];
    const float* t    = (const float*)d_in[1];
    const float* W_ih = (const float*)d_in[2];
    const float* W_hh = (const float*)d_in[3];
    const float* b_ih = (const float*)d_in[4];
    const float* b_hh = (const float*)d_in[5];
    const float* W1   = (const float*)d_in[6];
    const float* b1   = (const float*)d_in[7];
    const float* W2   = (const float*)d_in[8];
    const float* b2   = (const float*)d_in[9];
    float* out = (float*)d_out;

    hipLaunchKernelGGL(odegru_kernel, dim3(BATCH), dim3(256), 0, stream,
                       x, t, W_ih, W_hh, b_ih, b_hh, W1, b1, W2, b2, out);
}